// Round 5
// baseline (27.841 us; speedup 1.0000x reference)
//
#include <hip/hip_runtime.h>

#define POOL 7
#define FM_H 128
#define FM_W 128
#define FM_C 512
#define NGRP 16                // 16 channel groups of 32 ch -> 2 MiB fm slice each
#define CELLS_PER_BLK 32       // 256 threads = 32 cells x 8 lanes x float4 (32 ch)

typedef float f32x4 __attribute__((ext_vector_type(4)));

// Channel-partitioned ROI pooling, XCD-pinned, two-phase.
// XCD = blockIdx&7 (empirical round-robin). Groups 0-7 run in the first half
// of the grid, groups 8-15 in the second half -> each XCD has ONE 2 MiB fm
// slice resident at a time (R4: exactly-4MiB slice left zero L2 headroom).
__global__ __launch_bounds__(256) void roi_pool_kernel(
    const float* __restrict__ fm,    // [128,128,512] NHWC (batch 1)
    const float* __restrict__ rois,  // [R,4] = xmin,xmax,ymin,ymax (integral floats)
    float* __restrict__ out,         // [R,7,7,512]
    int n_cells,                     // R*49
    int half)                        // blocks per phase
{
    const int tid   = threadIdx.x;
    const int bid   = blockIdx.x;
    const int phase = (bid >= half) ? 1 : 0;
    const int b     = bid - phase * half;
    const int g     = (b & 7) + (phase << 3);        // channel group; XCD = b&7
    const int cb    = b >> 3;
    const int cell  = cb * CELLS_PER_BLK + (tid >> 3);
    if (cell >= n_cells) return;
    const int c4    = (g << 5) + ((tid & 7) << 2);   // g*32 + lane8*4

    const int r  = cell / (POOL * POOL);
    const int p  = cell - r * (POOL * POOL);
    const int py = p / POOL;
    const int px = p - py * POOL;

    // rois are integral values stored as f32; astype(int32) == truncation.
    const float4 rv = *reinterpret_cast<const float4*>(rois + (size_t)r * 4);
    const int xmin = (int)rv.x;
    const int xmax = (int)rv.y;
    const int ymin = (int)rv.z;
    const int ymax = (int)rv.w;
    const int sy = ymax - ymin;
    const int sx = xmax - xmin;

    // _axis_coords, replicated op-for-op in fp32 to match the reference.
    const float scy  = (float)sy / 7.0f;
    const float srcy = (float)py * scy;
    const int   iy0  = (int)floorf(srcy);
    const int   iy1  = min(iy0 + 1, sy - 1);
    const float fy   = srcy - (float)iy0;
    const int   y0   = ymin + iy0;
    const int   y1   = ymin + iy1;

    const float scx  = (float)sx / 7.0f;
    const float srcx = (float)px * scx;
    const int   ix0  = (int)floorf(srcx);
    const int   ix1  = min(ix0 + 1, sx - 1);
    const float fx   = srcx - (float)ix0;
    const int   x0   = xmin + ix0;
    const int   x1   = xmin + ix1;

    const size_t o00 = ((size_t)(y0 * FM_W + x0)) * FM_C + c4;
    const size_t o01 = ((size_t)(y0 * FM_W + x1)) * FM_C + c4;
    const size_t o10 = ((size_t)(y1 * FM_W + x0)) * FM_C + c4;
    const size_t o11 = ((size_t)(y1 * FM_W + x1)) * FM_C + c4;

    const float4 tl = *reinterpret_cast<const float4*>(fm + o00);
    const float4 tr = *reinterpret_cast<const float4*>(fm + o01);
    const float4 bl = *reinterpret_cast<const float4*>(fm + o10);
    const float4 br = *reinterpret_cast<const float4*>(fm + o11);

    f32x4 o;
    {
        float top, bot;
        top = tl.x + (tr.x - tl.x) * fx; bot = bl.x + (br.x - bl.x) * fx; o.x = top + (bot - top) * fy;
        top = tl.y + (tr.y - tl.y) * fx; bot = bl.y + (br.y - bl.y) * fx; o.y = top + (bot - top) * fy;
        top = tl.z + (tr.z - tl.z) * fx; bot = bl.z + (br.z - bl.z) * fx; o.z = top + (bot - top) * fy;
        top = tl.w + (tr.w - tl.w) * fx; bot = bl.w + (br.w - bl.w) * fx; o.w = top + (bot - top) * fy;
    }

    // Nontemporal streaming store — keep the write-once output out of L2.
    f32x4* dst = reinterpret_cast<f32x4*>(out + (size_t)cell * FM_C + c4);
    __builtin_nontemporal_store(o, dst);
}

extern "C" void kernel_launch(void* const* d_in, const int* in_sizes, int n_in,
                              void* d_out, int out_size, void* d_ws, size_t ws_size,
                              hipStream_t stream) {
    const float* fm   = (const float*)d_in[0];
    const float* rois = (const float*)d_in[1];
    float* out        = (float*)d_out;

    const int R       = in_sizes[1] / 4;
    const int n_cells = R * POOL * POOL;                                // 50176
    const int cblocks = (n_cells + CELLS_PER_BLK - 1) / CELLS_PER_BLK;  // 1568
    const int half    = cblocks * 8;                                    // 12544
    const int blocks  = half * 2;                                       // 25088

    roi_pool_kernel<<<blocks, 256, 0, stream>>>(fm, rois, out, n_cells, half);
}